// Round 1
// baseline (188.858 us; speedup 1.0000x reference)
//
#include <hip/hip_runtime.h>

// GCN layer: out[n] = (sum over edges e with dst[e]==n of w[e]*nodes[src[e]]) @ K
// N=65536 nodes, E=1048576 edges (dst sorted), D=UNITS=64.

constexpr int D = 64;
constexpr int EPW = 128;  // edges per wave (E/EPW = 8192 waves = 32 waves/CU)

__global__ __launch_bounds__(256) void zero_kernel(float4* __restrict__ p, int n4) {
    int i = blockIdx.x * blockDim.x + threadIdx.x;
    int stride = gridDim.x * blockDim.x;
    for (; i < n4; i += stride) p[i] = make_float4(0.f, 0.f, 0.f, 0.f);
}

// One wave per contiguous 128-edge chunk. lane = feature index (D == wave size).
// dst is sorted -> accumulate in a register, flush via atomicAdd on dst change.
__global__ __launch_bounds__(256) void scatter_kernel(
    const float* __restrict__ nodes, const float* __restrict__ evals,
    const int* __restrict__ src, const int* __restrict__ dst,
    float* __restrict__ out, int n_edges)
{
    const int lane = threadIdx.x & 63;
    const int wid  = blockIdx.x * (blockDim.x >> 6) + (threadIdx.x >> 6);
    const long base = (long)wid * EPW;
    if (base >= n_edges) return;

    float acc = 0.f;
    int prev = dst[base];  // wave-uniform (broadcast load)

    #pragma unroll 1
    for (int i0 = 0; i0 < EPW; i0 += 8) {
        int sv[8], dv[8]; float wv[8];
        #pragma unroll
        for (int j = 0; j < 8; ++j) {
            long e = base + i0 + j;
            sv[j] = src[e]; dv[j] = dst[e]; wv[j] = evals[e];
        }
        // 8 independent gathers in flight (each 256B coalesced per wave)
        float v[8];
        #pragma unroll
        for (int j = 0; j < 8; ++j) v[j] = nodes[(long)sv[j] * D + lane];
        #pragma unroll
        for (int j = 0; j < 8; ++j) {
            if (dv[j] != prev) {            // wave-uniform branch
                atomicAdd(&out[(long)prev * D + lane], acc);
                acc = 0.f;
                prev = dv[j];
            }
            acc = fmaf(wv[j], v[j], acc);
        }
    }
    atomicAdd(&out[(long)prev * D + lane], acc);
}

// In-place dense projection: row_out = row_agg @ K. One wave per node row.
__global__ __launch_bounds__(256) void project_inplace(
    float* __restrict__ out, const float* __restrict__ Km, int n_nodes)
{
    __shared__ float Ks[D * D];  // Ks[d][u], row-major
    const int t = threadIdx.x;
    for (int i = t; i < D * D; i += 256) Ks[i] = Km[i];
    __syncthreads();

    const int lane = t & 63;
    const int wave = t >> 6;
    const int n = blockIdx.x * 4 + wave;
    if (n >= n_nodes) return;

    float* row = out + (long)n * D;
    const float rv = row[lane];  // coalesced: lane holds agg[n][lane]
    float acc = 0.f;
    #pragma unroll
    for (int d = 0; d < D; ++d) {
        // broadcast agg[n][d] to all lanes; lane computes output unit `lane`
        acc = fmaf(__shfl(rv, d), Ks[d * D + lane], acc);
    }
    row[lane] = acc;  // safe: this wave is the only toucher of this row
}

extern "C" void kernel_launch(void* const* d_in, const int* in_sizes, int n_in,
                              void* d_out, int out_size, void* d_ws, size_t ws_size,
                              hipStream_t stream) {
    const float* nodes = (const float*)d_in[0];
    const float* evals = (const float*)d_in[1];
    const float* Km    = (const float*)d_in[2];
    const int*   src   = (const int*)d_in[3];
    const int*   dst   = (const int*)d_in[4];
    float* out = (float*)d_out;

    const int n_nodes = in_sizes[0] / D;
    const int n_edges = in_sizes[1];

    // 1) zero the (0xAA-poisoned) output, which doubles as the agg buffer
    zero_kernel<<<2048, 256, 0, stream>>>((float4*)out, out_size / 4);

    // 2) edge scatter-aggregate into out
    const int n_waves  = (n_edges + EPW - 1) / EPW;
    const int n_blocks = (n_waves + 3) / 4;
    scatter_kernel<<<n_blocks, 256, 0, stream>>>(nodes, evals, src, dst, out, n_edges);

    // 3) in-place projection by K
    project_inplace<<<(n_nodes + 3) / 4, 256, 0, stream>>>(out, Km, n_nodes);
}